// Round 2
// baseline (1834.405 us; speedup 1.0000x reference)
//
#include <hip/hip_runtime.h>

#define NN 100000
#define NE 500000
#define D 128
#define EPS 1e-5f
#define SLOPE 0.01f

// ---------------- CSR build ----------------
__global__ void count_deg(const int* __restrict__ dst, int E, int* __restrict__ deg) {
  int i = blockIdx.x * 256 + threadIdx.x;
  if (i < E) atomicAdd(&deg[dst[i]], 1);
}

__global__ void scan_block_sums(const int* __restrict__ deg, int* __restrict__ bsums, int n) {
  __shared__ int red[256];
  int base = blockIdx.x * 1024;
  int s = 0;
  for (int i = threadIdx.x; i < 1024; i += 256) {
    int idx = base + i;
    if (idx < n) s += deg[idx];
  }
  red[threadIdx.x] = s;
  __syncthreads();
  for (int off = 128; off > 0; off >>= 1) {
    if (threadIdx.x < off) red[threadIdx.x] += red[threadIdx.x + off];
    __syncthreads();
  }
  if (threadIdx.x == 0) bsums[blockIdx.x] = red[0];
}

__global__ void scan_top(int* bsums, int nb) {
  if (threadIdx.x == 0 && blockIdx.x == 0) {
    int run = 0;
    for (int i = 0; i < nb; ++i) { int v = bsums[i]; bsums[i] = run; run += v; }
  }
}

__global__ void scan_final(const int* __restrict__ deg, const int* __restrict__ bsums,
                           int* __restrict__ row_ptr, int* __restrict__ fill,
                           float* __restrict__ invdeg, int n, int Etot) {
  __shared__ int buf[2][256];
  int base = blockIdx.x * 1024;
  int v[4];
  int s = 0;
#pragma unroll
  for (int j = 0; j < 4; ++j) {
    int idx = base + threadIdx.x * 4 + j;
    v[j] = (idx < n) ? deg[idx] : 0;
    s += v[j];
  }
  buf[0][threadIdx.x] = s;
  __syncthreads();
  int cur = 0;
  for (int d2 = 1; d2 < 256; d2 <<= 1) {
    int val = buf[cur][threadIdx.x];
    if (threadIdx.x >= d2) val += buf[cur][threadIdx.x - d2];
    buf[cur ^ 1][threadIdx.x] = val;
    __syncthreads();
    cur ^= 1;
  }
  int run = buf[cur][threadIdx.x] - s + bsums[blockIdx.x];
#pragma unroll
  for (int j = 0; j < 4; ++j) {
    int idx = base + threadIdx.x * 4 + j;
    if (idx < n) {
      row_ptr[idx] = run;
      fill[idx] = run;
      int dv = v[j] < 1 ? 1 : v[j];
      invdeg[idx] = 1.0f / (float)dv;
      run += v[j];
    }
  }
  if (blockIdx.x == 0 && threadIdx.x == 0) row_ptr[n] = Etot;
}

__global__ void fill_csr(const int* __restrict__ src, const int* __restrict__ dst,
                         int* __restrict__ fill, int* __restrict__ col, int E) {
  int i = blockIdx.x * 256 + threadIdx.x;
  if (i < E) {
    int p = atomicAdd(&fill[dst[i]], 1);
    col[p] = src[i];
  }
}

// ---------------- weight packing: Wcat[128][384] = [Wn1 | Wn2 | Ws1+Ws2] ----------------
__global__ void pack_w(const float* __restrict__ Wn1, const float* __restrict__ Wn2,
                       const float* __restrict__ Ws1, const float* __restrict__ Ws2,
                       float* __restrict__ Wcat) {
  int i = blockIdx.x * 256 + threadIdx.x;
  if (i >= D * D) return;
  int k = i >> 7, c = i & (D - 1);
  float* row = Wcat + (size_t)k * 384;
  row[c] = Wn1[i];
  row[128 + c] = Wn2[i];
  row[256 + c] = Ws1[i] + Ws2[i];
}

// ---------------- wide GEMM: [Hn1|Hn2|Hs](row, strip) = X[row] @ Wcat[:, strip] ----------
// grid = (ceil(M/256), 12). Each thread: 1 row x 32 cols, acc[32] in VGPRs.
// W addresses are wave-uniform (scalar path); x row loads served by L1/L2.
__global__ __launch_bounds__(256) void gemm_x3(const float* __restrict__ X,
                                               const float* __restrict__ Wcat,
                                               float* __restrict__ Hn1,
                                               float* __restrict__ Hn2,
                                               float* __restrict__ Hs, int M) {
  int row = blockIdx.x * 256 + threadIdx.x;
  int strip = blockIdx.y;            // 0..11
  if (row >= M) return;
  const int col0 = strip * 32;       // column base in Wcat
  const float* x = X + (size_t)row * D;
  float acc[32];
#pragma unroll
  for (int c = 0; c < 32; ++c) acc[c] = 0.0f;
#pragma unroll 1
  for (int k = 0; k < D; k += 4) {
    float4 xv = *reinterpret_cast<const float4*>(x + k);
    float xs[4] = {xv.x, xv.y, xv.z, xv.w};
    const float* w0 = Wcat + (size_t)k * 384 + col0;
#pragma unroll
    for (int kk = 0; kk < 4; ++kk) {
      const float* wr = w0 + (size_t)kk * 384;  // wave-uniform
#pragma unroll
      for (int c = 0; c < 32; c += 4) {
        float4 wv = *reinterpret_cast<const float4*>(wr + c);
        acc[c + 0] = fmaf(xs[kk], wv.x, acc[c + 0]);
        acc[c + 1] = fmaf(xs[kk], wv.y, acc[c + 1]);
        acc[c + 2] = fmaf(xs[kk], wv.z, acc[c + 2]);
        acc[c + 3] = fmaf(xs[kk], wv.w, acc[c + 3]);
      }
    }
  }
  float* outs = (strip < 4) ? Hn1 : (strip < 8) ? Hn2 : Hs;
  float* y = outs + (size_t)row * D + (strip & 3) * 32;
#pragma unroll
  for (int c = 0; c < 32; c += 4) {
    float4 o;
    o.x = acc[c]; o.y = acc[c + 1]; o.z = acc[c + 2]; o.w = acc[c + 3];
    *reinterpret_cast<float4*>(y + c) = o;
  }
}

// ---------------- fused aggregation: Hs[n] += inv1*sum Hn1[col1] + inv2*sum Hn2[col2] ----
// In-place RMW on Hs (per-row independent). 4 nodes per 256-thread block.
__global__ void fused_agg(float* __restrict__ Hs, const float* __restrict__ Hn1,
                          const float* __restrict__ Hn2,
                          const int* __restrict__ rp1, const int* __restrict__ col1,
                          const float* __restrict__ inv1,
                          const int* __restrict__ rp2, const int* __restrict__ col2,
                          const float* __restrict__ inv2, int Nn) {
  int n = blockIdx.x * 4 + (threadIdx.x >> 6);
  if (n >= Nn) return;
  int t = (threadIdx.x & 63) * 2;
  float2 sv = *reinterpret_cast<const float2*>(Hs + (size_t)n * D + t);
  float a0 = 0.f, a1 = 0.f;
  int b1 = rp1[n], e1 = rp1[n + 1];
  for (int j = b1; j < e1; ++j) {
    float2 v = *reinterpret_cast<const float2*>(Hn1 + (size_t)col1[j] * D + t);
    a0 += v.x; a1 += v.y;
  }
  float i1 = inv1[n];
  float c0 = sv.x + a0 * i1, c1 = sv.y + a1 * i1;
  a0 = 0.f; a1 = 0.f;
  int b2 = rp2[n], e2 = rp2[n + 1];
  for (int j = b2; j < e2; ++j) {
    float2 v = *reinterpret_cast<const float2*>(Hn2 + (size_t)col2[j] * D + t);
    a0 += v.x; a1 += v.y;
  }
  float i2 = inv2[n];
  c0 += a0 * i2; c1 += a1 * i2;
  float2 o; o.x = c0; o.y = c1;
  *reinterpret_cast<float2*>(Hs + (size_t)n * D + t) = o;
}

// ---------------- BatchNorm ----------------
__global__ void bn_stats(const float* __restrict__ H, float* __restrict__ stats, int M) {
  int c = threadIdx.x & (D - 1);
  int half = threadIdx.x >> 7;
  int r = blockIdx.x * 256 + half;
  float s = 0.f, s2 = 0.f;
#pragma unroll 4
  for (int i = 0; i < 128; ++i, r += 2) {
    if (r < M) {
      float v = H[(size_t)r * D + c];
      s += v;
      s2 += v * v;
    }
  }
  atomicAdd(&stats[c], s);
  atomicAdd(&stats[D + c], s2);
}

// in-place BN + optional LeakyReLU
__global__ void bn_apply(float* __restrict__ H, const float* __restrict__ stats,
                         const float* __restrict__ g, const float* __restrict__ b,
                         int M, float invM, int leaky) {
  int i = blockIdx.x * 256 + threadIdx.x;
  size_t base = (size_t)i * 4;
  if (base >= (size_t)M * D) return;
  int c = (int)(base & (D - 1));
  float4 h = *reinterpret_cast<const float4*>(H + base);
  float hv[4] = {h.x, h.y, h.z, h.w};
  float ov[4];
#pragma unroll
  for (int q = 0; q < 4; ++q) {
    float mean = stats[c + q] * invM;
    float var = stats[D + c + q] * invM - mean * mean;
    float sc = rsqrtf(var + EPS) * g[c + q];
    float sh = b[c + q] - mean * sc;
    float v = hv[q] * sc + sh;
    if (leaky) v = v > 0.f ? v : SLOPE * v;
    ov[q] = v;
  }
  float4 o;
  o.x = ov[0]; o.y = ov[1]; o.z = ov[2]; o.w = ov[3];
  *reinterpret_cast<float4*>(H + base) = o;
}

// precompute per-column affine coefficients: coef[c]=scale, coef[128+c]=shift
__global__ void bn_coef(const float* __restrict__ stats, const float* __restrict__ g,
                        const float* __restrict__ b, float* __restrict__ coef, float invM) {
  int c = threadIdx.x;
  if (c >= D) return;
  float mean = stats[c] * invM;
  float var = stats[D + c] * invM - mean * mean;
  float s = rsqrtf(var + EPS) * g[c];
  coef[c] = s;
  coef[D + c] = b[c] - mean * s;
}

// ---------------- edge-label dots with fused BN affine ----------------
__global__ void edge_dot_bn(const float* __restrict__ H, const float* __restrict__ coef,
                            const int* __restrict__ ea, const int* __restrict__ eb,
                            float* __restrict__ out, int EL) {
  int tt = blockIdx.x * 256 + threadIdx.x;
  int e = tt >> 4, l = tt & 15;
  if (e >= EL) return;
  int cb = l * 8;
  float4 sc0 = *reinterpret_cast<const float4*>(coef + cb);
  float4 sc1 = *reinterpret_cast<const float4*>(coef + cb + 4);
  float4 sh0 = *reinterpret_cast<const float4*>(coef + D + cb);
  float4 sh1 = *reinterpret_cast<const float4*>(coef + D + cb + 4);
  const float* ha = H + (size_t)ea[e] * D + cb;
  const float* hb = H + (size_t)eb[e] * D + cb;
  float4 a0 = *reinterpret_cast<const float4*>(ha);
  float4 a1 = *reinterpret_cast<const float4*>(ha + 4);
  float4 b0 = *reinterpret_cast<const float4*>(hb);
  float4 b1 = *reinterpret_cast<const float4*>(hb + 4);
  a0.x = fmaf(a0.x, sc0.x, sh0.x); a0.y = fmaf(a0.y, sc0.y, sh0.y);
  a0.z = fmaf(a0.z, sc0.z, sh0.z); a0.w = fmaf(a0.w, sc0.w, sh0.w);
  a1.x = fmaf(a1.x, sc1.x, sh1.x); a1.y = fmaf(a1.y, sc1.y, sh1.y);
  a1.z = fmaf(a1.z, sc1.z, sh1.z); a1.w = fmaf(a1.w, sc1.w, sh1.w);
  b0.x = fmaf(b0.x, sc0.x, sh0.x); b0.y = fmaf(b0.y, sc0.y, sh0.y);
  b0.z = fmaf(b0.z, sc0.z, sh0.z); b0.w = fmaf(b0.w, sc0.w, sh0.w);
  b1.x = fmaf(b1.x, sc1.x, sh1.x); b1.y = fmaf(b1.y, sc1.y, sh1.y);
  b1.z = fmaf(b1.z, sc1.z, sh1.z); b1.w = fmaf(b1.w, sc1.w, sh1.w);
  float d = a0.x * b0.x + a0.y * b0.y + a0.z * b0.z + a0.w * b0.w +
            a1.x * b1.x + a1.y * b1.y + a1.z * b1.z + a1.w * b1.w;
  d += __shfl_xor(d, 1);
  d += __shfl_xor(d, 2);
  d += __shfl_xor(d, 4);
  d += __shfl_xor(d, 8);
  if (l == 0) out[e] = d;
}

// ---------------- launch ----------------
extern "C" void kernel_launch(void* const* d_in, const int* in_sizes, int n_in,
                              void* d_out, int out_size, void* d_ws, size_t ws_size,
                              hipStream_t stream) {
  const float* x   = (const float*)d_in[0];
  const int* ei1   = (const int*)d_in[1];
  const int* ei2   = (const int*)d_in[2];
  const int* eli   = (const int*)d_in[3];
  const float* W1n1 = (const float*)d_in[4];
  const float* W1s1 = (const float*)d_in[5];
  const float* W1n2 = (const float*)d_in[6];
  const float* W1s2 = (const float*)d_in[7];
  const float* W2n1 = (const float*)d_in[8];
  const float* W2s1 = (const float*)d_in[9];
  const float* W2n2 = (const float*)d_in[10];
  const float* W2s2 = (const float*)d_in[11];
  const float* g1  = (const float*)d_in[12];
  const float* b1  = (const float*)d_in[13];
  const float* g2  = (const float*)d_in[14];
  const float* b2  = (const float*)d_in[15];
  float* out = (float*)d_out;

  const int N = NN, E = NE;
  const int EL = in_sizes[3] / 2;

  char* w = (char*)d_ws;
  float* Hn1 = (float*)w; w += (size_t)N * D * 4;
  float* Hn2 = (float*)w; w += (size_t)N * D * 4;
  float* HsA = (float*)w; w += (size_t)N * D * 4;   // layer1 accum / layer2 input
  float* HsB = (float*)w; w += (size_t)N * D * 4;   // layer2 accum
  int* deg1 = (int*)w; w += (size_t)N * 4;
  int* deg2 = (int*)w; w += (size_t)N * 4;
  int* rp1  = (int*)w; w += (size_t)(N + 1) * 4;
  int* rp2  = (int*)w; w += (size_t)(N + 1) * 4;
  int* fl1  = (int*)w; w += (size_t)N * 4;
  int* fl2  = (int*)w; w += (size_t)N * 4;
  int* col1 = (int*)w; w += (size_t)E * 4;
  int* col2 = (int*)w; w += (size_t)E * 4;
  int* bsums = (int*)w; w += 256 * 4;
  float* inv1 = (float*)w; w += (size_t)N * 4;
  float* inv2 = (float*)w; w += (size_t)N * 4;
  float* stats1 = (float*)w; w += 2 * D * 4;
  float* stats2 = (float*)w; w += 2 * D * 4;
  float* coef = (float*)w; w += 2 * D * 4;
  float* Wcat1 = (float*)w; w += (size_t)D * 384 * 4;
  float* Wcat2 = (float*)w; w += (size_t)D * 384 * 4;

  hipMemsetAsync(deg1, 0, (size_t)2 * N * 4, stream);  // deg1+deg2 contiguous
  hipMemsetAsync(stats1, 0, 4 * D * 4, stream);        // stats1+stats2 contiguous

  int ebk = (E + 255) / 256;
  count_deg<<<ebk, 256, 0, stream>>>(ei1 + E, E, deg1);
  count_deg<<<ebk, 256, 0, stream>>>(ei2 + E, E, deg2);

  int nb = (N + 1023) / 1024;
  scan_block_sums<<<nb, 256, 0, stream>>>(deg1, bsums, N);
  scan_top<<<1, 64, 0, stream>>>(bsums, nb);
  scan_final<<<nb, 256, 0, stream>>>(deg1, bsums, rp1, fl1, inv1, N, E);
  scan_block_sums<<<nb, 256, 0, stream>>>(deg2, bsums, N);
  scan_top<<<1, 64, 0, stream>>>(bsums, nb);
  scan_final<<<nb, 256, 0, stream>>>(deg2, bsums, rp2, fl2, inv2, N, E);

  fill_csr<<<ebk, 256, 0, stream>>>(ei1, ei1 + E, fl1, col1, E);
  fill_csr<<<ebk, 256, 0, stream>>>(ei2, ei2 + E, fl2, col2, E);

  pack_w<<<(D * D + 255) / 256, 256, 0, stream>>>(W1n1, W1n2, W1s1, W1s2, Wcat1);
  pack_w<<<(D * D + 255) / 256, 256, 0, stream>>>(W2n1, W2n2, W2s1, W2s2, Wcat2);

  int gb = (N + 255) / 256;
  int ab = (int)(((size_t)N * D / 4 + 255) / 256);
  int agb = (N + 3) / 4;

  // ---- Layer 1 ----
  gemm_x3<<<dim3(gb, 12), 256, 0, stream>>>(x, Wcat1, Hn1, Hn2, HsA, N);
  fused_agg<<<agb, 256, 0, stream>>>(HsA, Hn1, Hn2, rp1, col1, inv1, rp2, col2, inv2, N);
  bn_stats<<<gb, 256, 0, stream>>>(HsA, stats1, N);
  bn_apply<<<ab, 256, 0, stream>>>(HsA, stats1, g1, b1, N, 1.0f / N, 1);

  // ---- Layer 2 ----
  gemm_x3<<<dim3(gb, 12), 256, 0, stream>>>(HsA, Wcat2, Hn1, Hn2, HsB, N);
  fused_agg<<<agb, 256, 0, stream>>>(HsB, Hn1, Hn2, rp1, col1, inv1, rp2, col2, inv2, N);
  bn_stats<<<gb, 256, 0, stream>>>(HsB, stats2, N);
  bn_coef<<<1, 128, 0, stream>>>(stats2, g2, b2, coef, 1.0f / N);

  // ---- edge-label dots (BN affine fused) ----
  int db = (int)(((size_t)EL * 16 + 255) / 256);
  edge_dot_bn<<<db, 256, 0, stream>>>(HsB, coef, eli, eli + EL, out, EL);
}

// Round 3
// 892.499 us; speedup vs baseline: 2.0554x; 2.0554x over previous
//
#include <hip/hip_runtime.h>

#define NN 100000
#define NE 500000
#define D 128
#define WT 384          // Wcat width / Hcat row stride
#define EPS 1e-5f
#define SLOPE 0.01f

// ---------------- CSR build ----------------
__global__ void count_deg(const int* __restrict__ dst, int E, int* __restrict__ deg) {
  int i = blockIdx.x * 256 + threadIdx.x;
  if (i < E) atomicAdd(&deg[dst[i]], 1);
}

__global__ void scan_block_sums(const int* __restrict__ deg, int* __restrict__ bsums, int n) {
  __shared__ int red[256];
  int base = blockIdx.x * 1024;
  int s = 0;
  for (int i = threadIdx.x; i < 1024; i += 256) {
    int idx = base + i;
    if (idx < n) s += deg[idx];
  }
  red[threadIdx.x] = s;
  __syncthreads();
  for (int off = 128; off > 0; off >>= 1) {
    if (threadIdx.x < off) red[threadIdx.x] += red[threadIdx.x + off];
    __syncthreads();
  }
  if (threadIdx.x == 0) bsums[blockIdx.x] = red[0];
}

__global__ void scan_top(int* bsums, int nb) {
  if (threadIdx.x == 0 && blockIdx.x == 0) {
    int run = 0;
    for (int i = 0; i < nb; ++i) { int v = bsums[i]; bsums[i] = run; run += v; }
  }
}

__global__ void scan_final(const int* __restrict__ deg, const int* __restrict__ bsums,
                           int* __restrict__ row_ptr, int* __restrict__ fill,
                           float* __restrict__ invdeg, int n, int Etot) {
  __shared__ int buf[2][256];
  int base = blockIdx.x * 1024;
  int v[4];
  int s = 0;
#pragma unroll
  for (int j = 0; j < 4; ++j) {
    int idx = base + threadIdx.x * 4 + j;
    v[j] = (idx < n) ? deg[idx] : 0;
    s += v[j];
  }
  buf[0][threadIdx.x] = s;
  __syncthreads();
  int cur = 0;
  for (int d2 = 1; d2 < 256; d2 <<= 1) {
    int val = buf[cur][threadIdx.x];
    if (threadIdx.x >= d2) val += buf[cur][threadIdx.x - d2];
    buf[cur ^ 1][threadIdx.x] = val;
    __syncthreads();
    cur ^= 1;
  }
  int run = buf[cur][threadIdx.x] - s + bsums[blockIdx.x];
#pragma unroll
  for (int j = 0; j < 4; ++j) {
    int idx = base + threadIdx.x * 4 + j;
    if (idx < n) {
      row_ptr[idx] = run;
      fill[idx] = run;
      int dv = v[j] < 1 ? 1 : v[j];
      invdeg[idx] = 1.0f / (float)dv;
      run += v[j];
    }
  }
  if (blockIdx.x == 0 && threadIdx.x == 0) row_ptr[n] = Etot;
}

__global__ void fill_csr(const int* __restrict__ src, const int* __restrict__ dst,
                         int* __restrict__ fill, int* __restrict__ col, int E) {
  int i = blockIdx.x * 256 + threadIdx.x;
  if (i < E) {
    int p = atomicAdd(&fill[dst[i]], 1);
    col[p] = src[i];
  }
}

// ---------------- weight packing: Wcat[128][384] = [Wn1 | Wn2 | Ws1+Ws2] ----------------
__global__ void pack_w(const float* __restrict__ Wn1, const float* __restrict__ Wn2,
                       const float* __restrict__ Ws1, const float* __restrict__ Ws2,
                       float* __restrict__ Wcat) {
  int i = blockIdx.x * 256 + threadIdx.x;
  if (i >= D * D) return;
  int k = i >> 7, c = i & (D - 1);
  float* row = Wcat + (size_t)k * WT;
  row[c] = Wn1[i];
  row[128 + c] = Wn2[i];
  row[256 + c] = Ws1[i] + Ws2[i];
}

// ---------------- LDS-staged GEMM: Hcat[row,0:384] = X[row,0:128] @ Wcat ----------------
// Block: 256 threads = 4 waves; 64 rows/block; wave w owns cols [w*96, w*96+96).
// X tile staged in LDS coalesced (read once); W via wave-uniform s_load.
__global__ __launch_bounds__(256) void gemm_x3(const float* __restrict__ X,
                                               const float* __restrict__ Wcat,
                                               float* __restrict__ Hcat, int M) {
  __shared__ float xs[64 * 129];   // stride 129: read bank = (row+k)&31 -> 2-way (free)
  const int t = threadIdx.x;
  const int row0 = blockIdx.x * 64;
  // ---- stage 64x128 tile, coalesced float4 loads ----
#pragma unroll
  for (int i = 0; i < 8; ++i) {
    int idx = i * 1024 + t * 4;        // flat float index in tile
    int r = idx >> 7, c = idx & 127;
    float4 v = make_float4(0.f, 0.f, 0.f, 0.f);
    if (row0 + r < M) v = *reinterpret_cast<const float4*>(X + (size_t)(row0 + r) * D + c);
    float* p = xs + r * 129 + c;       // stride 129 breaks float4 align -> scalar writes (one-time)
    p[0] = v.x; p[1] = v.y; p[2] = v.z; p[3] = v.w;
  }
  __syncthreads();

  const int lane = t & 63;                                        // row within tile
  const int cg = __builtin_amdgcn_readfirstlane(t >> 6);          // wave-uniform col group
  const float* wb = Wcat + cg * 96;
  float acc[96];
#pragma unroll
  for (int c = 0; c < 96; ++c) acc[c] = 0.f;

  const float* xrow = xs + lane * 129;
#pragma unroll 4
  for (int k = 0; k < D; ++k) {
    float xv = xrow[k];
    const float* wr = wb + (size_t)k * WT;   // wave-uniform -> s_load
#pragma unroll
    for (int c = 0; c < 96; c += 4) {
      float4 wv = *reinterpret_cast<const float4*>(wr + c);
      acc[c + 0] = fmaf(xv, wv.x, acc[c + 0]);
      acc[c + 1] = fmaf(xv, wv.y, acc[c + 1]);
      acc[c + 2] = fmaf(xv, wv.z, acc[c + 2]);
      acc[c + 3] = fmaf(xv, wv.w, acc[c + 3]);
    }
  }

  int row = row0 + lane;
  if (row < M) {
    float* dst = Hcat + (size_t)row * WT + cg * 96;
#pragma unroll
    for (int c = 0; c < 96; c += 4) {
      float4 o;
      o.x = acc[c]; o.y = acc[c + 1]; o.z = acc[c + 2]; o.w = acc[c + 3];
      *reinterpret_cast<float4*>(dst + c) = o;
    }
  }
}

// ---------------- fused aggregation on Hcat rows ----------------
// Hs(n) += inv1*sum Hn1(col1) + inv2*sum Hn2(col2); Hn1=+0, Hn2=+128, Hs=+256 (stride 384)
__global__ void fused_agg(float* __restrict__ Hcat,
                          const int* __restrict__ rp1, const int* __restrict__ col1,
                          const float* __restrict__ inv1,
                          const int* __restrict__ rp2, const int* __restrict__ col2,
                          const float* __restrict__ inv2, int Nn) {
  int n = blockIdx.x * 4 + (threadIdx.x >> 6);
  if (n >= Nn) return;
  int t2 = (threadIdx.x & 63) * 2;
  float* hs = Hcat + (size_t)n * WT + 256 + t2;
  float2 sv = *reinterpret_cast<const float2*>(hs);
  float a0 = 0.f, a1 = 0.f;
  int b1 = rp1[n], e1 = rp1[n + 1];
  for (int j = b1; j < e1; ++j) {
    float2 v = *reinterpret_cast<const float2*>(Hcat + (size_t)col1[j] * WT + t2);
    a0 += v.x; a1 += v.y;
  }
  float i1 = inv1[n];
  float c0 = sv.x + a0 * i1, c1 = sv.y + a1 * i1;
  a0 = 0.f; a1 = 0.f;
  int b2 = rp2[n], e2 = rp2[n + 1];
  for (int j = b2; j < e2; ++j) {
    float2 v = *reinterpret_cast<const float2*>(Hcat + (size_t)col2[j] * WT + 128 + t2);
    a0 += v.x; a1 += v.y;
  }
  float i2 = inv2[n];
  c0 += a0 * i2; c1 += a1 * i2;
  float2 o; o.x = c0; o.y = c1;
  *reinterpret_cast<float2*>(hs) = o;
}

// ---------------- BatchNorm (on Hs part of Hcat, stride 384) ----------------
__global__ void bn_stats(const float* __restrict__ Hs384, float* __restrict__ stats, int M) {
  int c = threadIdx.x & (D - 1);
  int half = threadIdx.x >> 7;
  int r = blockIdx.x * 256 + half;
  float s = 0.f, s2 = 0.f;
#pragma unroll 4
  for (int i = 0; i < 128; ++i, r += 2) {
    if (r < M) {
      float v = Hs384[(size_t)r * WT + c];
      s += v;
      s2 += v * v;
    }
  }
  atomicAdd(&stats[c], s);
  atomicAdd(&stats[D + c], s2);
}

// BN + LeakyReLU: read Hs (stride 384), write compact A[M][128]
__global__ void bn_apply(const float* __restrict__ Hs384, const float* __restrict__ stats,
                         const float* __restrict__ g, const float* __restrict__ b,
                         float* __restrict__ A, int M, float invM) {
  int i = blockIdx.x * 256 + threadIdx.x;
  size_t base = (size_t)i * 4;
  if (base >= (size_t)M * D) return;
  int row = (int)(base >> 7);
  int c = (int)(base & (D - 1));
  float4 h = *reinterpret_cast<const float4*>(Hs384 + (size_t)row * WT + c);
  float hv[4] = {h.x, h.y, h.z, h.w};
  float ov[4];
#pragma unroll
  for (int q = 0; q < 4; ++q) {
    float mean = stats[c + q] * invM;
    float var = stats[D + c + q] * invM - mean * mean;
    float sc = rsqrtf(var + EPS) * g[c + q];
    float sh = b[c + q] - mean * sc;
    float v = hv[q] * sc + sh;
    ov[q] = v > 0.f ? v : SLOPE * v;
  }
  float4 o;
  o.x = ov[0]; o.y = ov[1]; o.z = ov[2]; o.w = ov[3];
  *reinterpret_cast<float4*>(A + base) = o;
}

// per-column affine coefficients for final BN: coef[c]=scale, coef[128+c]=shift
__global__ void bn_coef(const float* __restrict__ stats, const float* __restrict__ g,
                        const float* __restrict__ b, float* __restrict__ coef, float invM) {
  int c = threadIdx.x;
  if (c >= D) return;
  float mean = stats[c] * invM;
  float var = stats[D + c] * invM - mean * mean;
  float s = rsqrtf(var + EPS) * g[c];
  coef[c] = s;
  coef[D + c] = b[c] - mean * s;
}

// ---------------- edge-label dots with fused BN affine (Hs in Hcat, stride 384) --------
__global__ void edge_dot_bn(const float* __restrict__ Hs384, const float* __restrict__ coef,
                            const int* __restrict__ ea, const int* __restrict__ eb,
                            float* __restrict__ out, int EL) {
  int tt = blockIdx.x * 256 + threadIdx.x;
  int e = tt >> 4, l = tt & 15;
  if (e >= EL) return;
  int cb = l * 8;
  float4 sc0 = *reinterpret_cast<const float4*>(coef + cb);
  float4 sc1 = *reinterpret_cast<const float4*>(coef + cb + 4);
  float4 sh0 = *reinterpret_cast<const float4*>(coef + D + cb);
  float4 sh1 = *reinterpret_cast<const float4*>(coef + D + cb + 4);
  const float* ha = Hs384 + (size_t)ea[e] * WT + cb;
  const float* hb = Hs384 + (size_t)eb[e] * WT + cb;
  float4 a0 = *reinterpret_cast<const float4*>(ha);
  float4 a1 = *reinterpret_cast<const float4*>(ha + 4);
  float4 b0 = *reinterpret_cast<const float4*>(hb);
  float4 b1 = *reinterpret_cast<const float4*>(hb + 4);
  a0.x = fmaf(a0.x, sc0.x, sh0.x); a0.y = fmaf(a0.y, sc0.y, sh0.y);
  a0.z = fmaf(a0.z, sc0.z, sh0.z); a0.w = fmaf(a0.w, sc0.w, sh0.w);
  a1.x = fmaf(a1.x, sc1.x, sh1.x); a1.y = fmaf(a1.y, sc1.y, sh1.y);
  a1.z = fmaf(a1.z, sc1.z, sh1.z); a1.w = fmaf(a1.w, sc1.w, sh1.w);
  b0.x = fmaf(b0.x, sc0.x, sh0.x); b0.y = fmaf(b0.y, sc0.y, sh0.y);
  b0.z = fmaf(b0.z, sc0.z, sh0.z); b0.w = fmaf(b0.w, sc0.w, sh0.w);
  b1.x = fmaf(b1.x, sc1.x, sh1.x); b1.y = fmaf(b1.y, sc1.y, sh1.y);
  b1.z = fmaf(b1.z, sc1.z, sh1.z); b1.w = fmaf(b1.w, sc1.w, sh1.w);
  float d = a0.x * b0.x + a0.y * b0.y + a0.z * b0.z + a0.w * b0.w +
            a1.x * b1.x + a1.y * b1.y + a1.z * b1.z + a1.w * b1.w;
  d += __shfl_xor(d, 1);
  d += __shfl_xor(d, 2);
  d += __shfl_xor(d, 4);
  d += __shfl_xor(d, 8);
  if (l == 0) out[e] = d;
}

// ---------------- launch ----------------
extern "C" void kernel_launch(void* const* d_in, const int* in_sizes, int n_in,
                              void* d_out, int out_size, void* d_ws, size_t ws_size,
                              hipStream_t stream) {
  const float* x   = (const float*)d_in[0];
  const int* ei1   = (const int*)d_in[1];
  const int* ei2   = (const int*)d_in[2];
  const int* eli   = (const int*)d_in[3];
  const float* W1n1 = (const float*)d_in[4];
  const float* W1s1 = (const float*)d_in[5];
  const float* W1n2 = (const float*)d_in[6];
  const float* W1s2 = (const float*)d_in[7];
  const float* W2n1 = (const float*)d_in[8];
  const float* W2s1 = (const float*)d_in[9];
  const float* W2n2 = (const float*)d_in[10];
  const float* W2s2 = (const float*)d_in[11];
  const float* g1  = (const float*)d_in[12];
  const float* b1  = (const float*)d_in[13];
  const float* g2  = (const float*)d_in[14];
  const float* b2  = (const float*)d_in[15];
  float* out = (float*)d_out;

  const int N = NN, E = NE;
  const int EL = in_sizes[3] / 2;

  char* w = (char*)d_ws;
  float* Hcat = (float*)w; w += (size_t)N * WT * 4;   // [Hn1|Hn2|Hs], reused by both layers
  float* A    = (float*)w; w += (size_t)N * D * 4;    // layer-1 output (compact)
  int* deg1 = (int*)w; w += (size_t)N * 4;
  int* deg2 = (int*)w; w += (size_t)N * 4;
  int* rp1  = (int*)w; w += (size_t)(N + 1) * 4;
  int* rp2  = (int*)w; w += (size_t)(N + 1) * 4;
  int* fl1  = (int*)w; w += (size_t)N * 4;
  int* fl2  = (int*)w; w += (size_t)N * 4;
  int* col1 = (int*)w; w += (size_t)E * 4;
  int* col2 = (int*)w; w += (size_t)E * 4;
  int* bsums = (int*)w; w += 256 * 4;
  float* inv1 = (float*)w; w += (size_t)N * 4;
  float* inv2 = (float*)w; w += (size_t)N * 4;
  float* stats1 = (float*)w; w += 2 * D * 4;
  float* stats2 = (float*)w; w += 2 * D * 4;
  float* coef = (float*)w; w += 2 * D * 4;
  float* Wcat1 = (float*)w; w += (size_t)D * WT * 4;
  float* Wcat2 = (float*)w; w += (size_t)D * WT * 4;

  hipMemsetAsync(deg1, 0, (size_t)2 * N * 4, stream);  // deg1+deg2 contiguous
  hipMemsetAsync(stats1, 0, 4 * D * 4, stream);        // stats1+stats2 contiguous

  int ebk = (E + 255) / 256;
  count_deg<<<ebk, 256, 0, stream>>>(ei1 + E, E, deg1);
  count_deg<<<ebk, 256, 0, stream>>>(ei2 + E, E, deg2);

  int nb = (N + 1023) / 1024;
  scan_block_sums<<<nb, 256, 0, stream>>>(deg1, bsums, N);
  scan_top<<<1, 64, 0, stream>>>(bsums, nb);
  scan_final<<<nb, 256, 0, stream>>>(deg1, bsums, rp1, fl1, inv1, N, E);
  scan_block_sums<<<nb, 256, 0, stream>>>(deg2, bsums, N);
  scan_top<<<1, 64, 0, stream>>>(bsums, nb);
  scan_final<<<nb, 256, 0, stream>>>(deg2, bsums, rp2, fl2, inv2, N, E);

  fill_csr<<<ebk, 256, 0, stream>>>(ei1, ei1 + E, fl1, col1, E);
  fill_csr<<<ebk, 256, 0, stream>>>(ei2, ei2 + E, fl2, col2, E);

  pack_w<<<(D * D + 255) / 256, 256, 0, stream>>>(W1n1, W1n2, W1s1, W1s2, Wcat1);
  pack_w<<<(D * D + 255) / 256, 256, 0, stream>>>(W2n1, W2n2, W2s1, W2s2, Wcat2);

  int gb64 = (N + 63) / 64;
  int gb = (N + 255) / 256;
  int ab = (int)(((size_t)N * D / 4 + 255) / 256);
  int agb = (N + 3) / 4;
  float* Hs384 = Hcat + 256;

  // ---- Layer 1 ----
  gemm_x3<<<gb64, 256, 0, stream>>>(x, Wcat1, Hcat, N);
  fused_agg<<<agb, 256, 0, stream>>>(Hcat, rp1, col1, inv1, rp2, col2, inv2, N);
  bn_stats<<<gb, 256, 0, stream>>>(Hs384, stats1, N);
  bn_apply<<<ab, 256, 0, stream>>>(Hs384, stats1, g1, b1, A, N, 1.0f / N);

  // ---- Layer 2 (Hcat reused) ----
  gemm_x3<<<gb64, 256, 0, stream>>>(A, Wcat2, Hcat, N);
  fused_agg<<<agb, 256, 0, stream>>>(Hcat, rp1, col1, inv1, rp2, col2, inv2, N);
  bn_stats<<<gb, 256, 0, stream>>>(Hs384, stats2, N);
  bn_coef<<<1, 128, 0, stream>>>(stats2, g2, b2, coef, 1.0f / N);

  // ---- edge-label dots (BN affine fused) ----
  int db = (int)(((size_t)EL * 16 + 255) / 256);
  edge_dot_bn<<<db, 256, 0, stream>>>(Hs384, coef, eli, eli + EL, out, EL);
}

// Round 4
// 717.999 us; speedup vs baseline: 2.5549x; 1.2430x over previous
//
#include <hip/hip_runtime.h>

#define NN 100000
#define NE 500000
#define D 128
#define EPS 1e-5f
#define SLOPE 0.01f

typedef short bf16x8 __attribute__((ext_vector_type(8)));
typedef float f32x4 __attribute__((ext_vector_type(4)));

__device__ __forceinline__ ushort f2bf(float x) {
  uint u = __float_as_uint(x);
  u += 0x7FFF + ((u >> 16) & 1);
  return (ushort)(u >> 16);
}
__device__ __forceinline__ float bf2f(ushort h) {
  return __uint_as_float(((uint)h) << 16);
}

// ---------------- CSR build ----------------
__global__ void count_deg(const int* __restrict__ dst, int E, int* __restrict__ deg) {
  int i = blockIdx.x * 256 + threadIdx.x;
  if (i < E) atomicAdd(&deg[dst[i]], 1);
}

__global__ void scan_block_sums(const int* __restrict__ deg, int* __restrict__ bsums, int n) {
  __shared__ int red[256];
  int base = blockIdx.x * 1024;
  int s = 0;
  for (int i = threadIdx.x; i < 1024; i += 256) {
    int idx = base + i;
    if (idx < n) s += deg[idx];
  }
  red[threadIdx.x] = s;
  __syncthreads();
  for (int off = 128; off > 0; off >>= 1) {
    if (threadIdx.x < off) red[threadIdx.x] += red[threadIdx.x + off];
    __syncthreads();
  }
  if (threadIdx.x == 0) bsums[blockIdx.x] = red[0];
}

__global__ void scan_top(int* bsums, int nb) {
  if (threadIdx.x == 0 && blockIdx.x == 0) {
    int run = 0;
    for (int i = 0; i < nb; ++i) { int v = bsums[i]; bsums[i] = run; run += v; }
  }
}

__global__ void scan_final(const int* __restrict__ deg, const int* __restrict__ bsums,
                           int* __restrict__ row_ptr, int* __restrict__ fill,
                           float* __restrict__ invdeg, int n, int Etot) {
  __shared__ int buf[2][256];
  int base = blockIdx.x * 1024;
  int v[4];
  int s = 0;
#pragma unroll
  for (int j = 0; j < 4; ++j) {
    int idx = base + threadIdx.x * 4 + j;
    v[j] = (idx < n) ? deg[idx] : 0;
    s += v[j];
  }
  buf[0][threadIdx.x] = s;
  __syncthreads();
  int cur = 0;
  for (int d2 = 1; d2 < 256; d2 <<= 1) {
    int val = buf[cur][threadIdx.x];
    if (threadIdx.x >= d2) val += buf[cur][threadIdx.x - d2];
    buf[cur ^ 1][threadIdx.x] = val;
    __syncthreads();
    cur ^= 1;
  }
  int run = buf[cur][threadIdx.x] - s + bsums[blockIdx.x];
#pragma unroll
  for (int j = 0; j < 4; ++j) {
    int idx = base + threadIdx.x * 4 + j;
    if (idx < n) {
      row_ptr[idx] = run;
      fill[idx] = run;
      int dv = v[j] < 1 ? 1 : v[j];
      invdeg[idx] = 1.0f / (float)dv;
      run += v[j];
    }
  }
  if (blockIdx.x == 0 && threadIdx.x == 0) row_ptr[n] = Etot;
}

__global__ void fill_csr(const int* __restrict__ src, const int* __restrict__ dst,
                         int* __restrict__ fill, int* __restrict__ col, int E) {
  int i = blockIdx.x * 256 + threadIdx.x;
  if (i < E) {
    int p = atomicAdd(&fill[dst[i]], 1);
    col[p] = src[i];
  }
}

// ---------------- weight pack into B-fragment order (hi/lo split) ----------------
// Wpack[((ct*4+ks)*64+l)] = bf16x8 of W[ks*32+(l>>4)*8 + j][ctcol], ct: 0-7 Wn1, 8-15 Wn2, 16-23 Ws1+Ws2
__global__ void wpack(const float* __restrict__ Wn1, const float* __restrict__ Wn2,
                      const float* __restrict__ Ws1, const float* __restrict__ Ws2,
                      bf16x8* __restrict__ Wh, bf16x8* __restrict__ Wl) {
  int ct = blockIdx.x;            // 0..23
  int ks = threadIdx.x >> 6;      // 0..3
  int l = threadIdx.x & 63;
  int col = (ct & 7) * 16 + (l & 15);
  int k0 = ks * 32 + (l >> 4) * 8;
  bf16x8 hv, lv;
#pragma unroll
  for (int j = 0; j < 8; ++j) {
    int k = k0 + j;
    float v;
    if (ct < 8)       v = Wn1[k * D + col];
    else if (ct < 16) v = Wn2[k * D + col];
    else              v = Ws1[k * D + col] + Ws2[k * D + col];
    ushort h = f2bf(v);
    float r = v - bf2f(h);
    hv[j] = (short)h;
    lv[j] = (short)f2bf(r);
  }
  int idx = (ct * 4 + ks) * 64 + l;
  Wh[idx] = hv;
  Wl[idx] = lv;
}

// ---------------- X pack into A-fragment order (hi/lo split) ----------------
// grid = Gtot (row-tiles of 16), block 256 = (ks 0..3) x (lane 0..63)
__global__ void xpack(const float* __restrict__ X, bf16x8* __restrict__ Xh,
                      bf16x8* __restrict__ Xl, int M) {
  int g = blockIdx.x;
  int ks = threadIdx.x >> 6;
  int l = threadIdx.x & 63;
  int row = g * 16 + (l & 15);
  int c0 = ks * 32 + (l >> 4) * 8;
  bf16x8 hv, lv;
  if (row < M) {
    float4 a = *reinterpret_cast<const float4*>(X + (size_t)row * D + c0);
    float4 b = *reinterpret_cast<const float4*>(X + (size_t)row * D + c0 + 4);
    float xs[8] = {a.x, a.y, a.z, a.w, b.x, b.y, b.z, b.w};
#pragma unroll
    for (int j = 0; j < 8; ++j) {
      ushort h = f2bf(xs[j]);
      float r = xs[j] - bf2f(h);
      hv[j] = (short)h;
      lv[j] = (short)f2bf(r);
    }
  } else {
#pragma unroll
    for (int j = 0; j < 8; ++j) { hv[j] = 0; lv[j] = 0; }
  }
  int idx = (g * 4 + ks) * 64 + l;
  Xh[idx] = hv;
  Xl[idx] = lv;
}

// ---------------- MFMA GEMM: [Hn1b|Hn2b|Hs] = X @ [Wn1|Wn2|Wsum] ----------------
// Block: 256 thr = 4 waves, 64 rows. Wave w owns col-tiles {w+4i}. Split-bf16 3-term.
__global__ __launch_bounds__(256) void gemm_mfma(
    const bf16x8* __restrict__ Xh, const bf16x8* __restrict__ Xl,
    const bf16x8* __restrict__ Wh, const bf16x8* __restrict__ Wl,
    ushort* __restrict__ Hn1b, ushort* __restrict__ Hn2b,
    float* __restrict__ Hs, int M) {
  int w = __builtin_amdgcn_readfirstlane(threadIdx.x >> 6);
  int l = threadIdx.x & 63;
  int rb = blockIdx.x;

  f32x4 acc[4][6];
#pragma unroll
  for (int rt = 0; rt < 4; ++rt)
#pragma unroll
    for (int i = 0; i < 6; ++i)
      acc[rt][i] = (f32x4){0.f, 0.f, 0.f, 0.f};

#pragma unroll
  for (int ks = 0; ks < 4; ++ks) {
    bf16x8 Ah[4], Al[4];
#pragma unroll
    for (int rt = 0; rt < 4; ++rt) {
      int gi = ((rb * 4 + rt) * 4 + ks) * 64 + l;
      Ah[rt] = Xh[gi];
      Al[rt] = Xl[gi];
    }
#pragma unroll
    for (int i = 0; i < 6; ++i) {
      int ct = w + 4 * i;
      int wi = (ct * 4 + ks) * 64 + l;
      bf16x8 bh = Wh[wi];
      bf16x8 bl = Wl[wi];
#pragma unroll
      for (int rt = 0; rt < 4; ++rt) {
        acc[rt][i] = __builtin_amdgcn_mfma_f32_16x16x32_bf16(Ah[rt], bh, acc[rt][i], 0, 0, 0);
        acc[rt][i] = __builtin_amdgcn_mfma_f32_16x16x32_bf16(Ah[rt], bl, acc[rt][i], 0, 0, 0);
        acc[rt][i] = __builtin_amdgcn_mfma_f32_16x16x32_bf16(Al[rt], bh, acc[rt][i], 0, 0, 0);
      }
    }
  }

  // store: lane l, reg r -> row (l>>4)*4+r, col l&15 of each 16x16 tile
  int cq = l & 15;
  int rq = (l >> 4) * 4;
#pragma unroll
  for (int i = 0; i < 6; ++i) {
    int ct = w + 4 * i;  // wave-uniform
#pragma unroll
    for (int rt = 0; rt < 4; ++rt) {
      int R0 = rb * 64 + rt * 16 + rq;
#pragma unroll
      for (int r = 0; r < 4; ++r) {
        int R = R0 + r;
        if (R < M) {
          float v = acc[rt][i][r];
          if (ct < 8) {
            Hn1b[(size_t)R * D + ct * 16 + cq] = f2bf(v);
          } else if (ct < 16) {
            Hn2b[(size_t)R * D + (ct - 8) * 16 + cq] = f2bf(v);
          } else {
            Hs[(size_t)R * D + (ct - 16) * 16 + cq] = v;
          }
        }
      }
    }
  }
}

// ---------------- fused aggregation: Hs[n] += inv1*sum Hn1b[col1] + inv2*sum Hn2b[col2] --
__global__ void fused_agg(float* __restrict__ Hs, const ushort* __restrict__ Hn1b,
                          const ushort* __restrict__ Hn2b,
                          const int* __restrict__ rp1, const int* __restrict__ col1,
                          const float* __restrict__ inv1,
                          const int* __restrict__ rp2, const int* __restrict__ col2,
                          const float* __restrict__ inv2, int Nn) {
  int n = blockIdx.x * 4 + (threadIdx.x >> 6);
  if (n >= Nn) return;
  int t2 = (threadIdx.x & 63) * 2;
  float* hs = Hs + (size_t)n * D + t2;
  float2 sv = *reinterpret_cast<const float2*>(hs);
  float a0 = 0.f, a1 = 0.f;
  int b1 = rp1[n], e1 = rp1[n + 1];
  for (int j = b1; j < e1; ++j) {
    uint v = *reinterpret_cast<const uint*>(Hn1b + (size_t)col1[j] * D + t2);
    a0 += bf2f((ushort)(v & 0xFFFF));
    a1 += bf2f((ushort)(v >> 16));
  }
  float i1 = inv1[n];
  float c0 = sv.x + a0 * i1, c1 = sv.y + a1 * i1;
  a0 = 0.f; a1 = 0.f;
  int b2 = rp2[n], e2 = rp2[n + 1];
  for (int j = b2; j < e2; ++j) {
    uint v = *reinterpret_cast<const uint*>(Hn2b + (size_t)col2[j] * D + t2);
    a0 += bf2f((ushort)(v & 0xFFFF));
    a1 += bf2f((ushort)(v >> 16));
  }
  float i2 = inv2[n];
  c0 += a0 * i2;
  c1 += a1 * i2;
  float2 o; o.x = c0; o.y = c1;
  *reinterpret_cast<float2*>(hs) = o;
}

// ---------------- BatchNorm stats (compact Hs [M][128]) ----------------
__global__ void bn_stats(const float* __restrict__ Hs, float* __restrict__ stats, int M) {
  int c = threadIdx.x & (D - 1);
  int half = threadIdx.x >> 7;
  int r = blockIdx.x * 256 + half;
  float s = 0.f, s2 = 0.f;
#pragma unroll 4
  for (int i = 0; i < 128; ++i, r += 2) {
    if (r < M) {
      float v = Hs[(size_t)r * D + c];
      s += v;
      s2 += v * v;
    }
  }
  atomicAdd(&stats[c], s);
  atomicAdd(&stats[D + c], s2);
}

// per-column affine: coef[c]=scale, coef[128+c]=shift
__global__ void bn_coef(const float* __restrict__ stats, const float* __restrict__ g,
                        const float* __restrict__ b, float* __restrict__ coef, float invM) {
  int c = threadIdx.x;
  if (c >= D) return;
  float mean = stats[c] * invM;
  float var = stats[D + c] * invM - mean * mean;
  float s = rsqrtf(var + EPS) * g[c];
  coef[c] = s;
  coef[D + c] = b[c] - mean * s;
}

// ---------------- BN + LeakyReLU + split-pack into A-fragment order ----------------
__global__ void bn_apply_pack(const float* __restrict__ Hs, const float* __restrict__ coef,
                              bf16x8* __restrict__ Ah, bf16x8* __restrict__ Al, int M) {
  int g = blockIdx.x;
  int ks = threadIdx.x >> 6;
  int l = threadIdx.x & 63;
  int row = g * 16 + (l & 15);
  int c0 = ks * 32 + (l >> 4) * 8;
  bf16x8 hv, lv;
  if (row < M) {
    float4 a = *reinterpret_cast<const float4*>(Hs + (size_t)row * D + c0);
    float4 b = *reinterpret_cast<const float4*>(Hs + (size_t)row * D + c0 + 4);
    float xs[8] = {a.x, a.y, a.z, a.w, b.x, b.y, b.z, b.w};
#pragma unroll
    for (int j = 0; j < 8; ++j) {
      int c = c0 + j;
      float v = fmaf(xs[j], coef[c], coef[D + c]);
      v = v > 0.f ? v : SLOPE * v;
      ushort h = f2bf(v);
      float r = v - bf2f(h);
      hv[j] = (short)h;
      lv[j] = (short)f2bf(r);
    }
  } else {
#pragma unroll
    for (int j = 0; j < 8; ++j) { hv[j] = 0; lv[j] = 0; }
  }
  int idx = (g * 4 + ks) * 64 + l;
  Ah[idx] = hv;
  Al[idx] = lv;
}

// ---------------- edge-label dots with fused BN affine (fp32 Hs) ----------------
__global__ void edge_dot_bn(const float* __restrict__ Hs, const float* __restrict__ coef,
                            const int* __restrict__ ea, const int* __restrict__ eb,
                            float* __restrict__ out, int EL) {
  int tt = blockIdx.x * 256 + threadIdx.x;
  int e = tt >> 4, l = tt & 15;
  if (e >= EL) return;
  int cb = l * 8;
  float4 sc0 = *reinterpret_cast<const float4*>(coef + cb);
  float4 sc1 = *reinterpret_cast<const float4*>(coef + cb + 4);
  float4 sh0 = *reinterpret_cast<const float4*>(coef + D + cb);
  float4 sh1 = *reinterpret_cast<const float4*>(coef + D + cb + 4);
  const float* ha = Hs + (size_t)ea[e] * D + cb;
  const float* hb = Hs + (size_t)eb[e] * D + cb;
  float4 a0 = *reinterpret_cast<const float4*>(ha);
  float4 a1 = *reinterpret_cast<const float4*>(ha + 4);
  float4 b0 = *reinterpret_cast<const float4*>(hb);
  float4 b1 = *reinterpret_cast<const float4*>(hb + 4);
  a0.x = fmaf(a0.x, sc0.x, sh0.x); a0.y = fmaf(a0.y, sc0.y, sh0.y);
  a0.z = fmaf(a0.z, sc0.z, sh0.z); a0.w = fmaf(a0.w, sc0.w, sh0.w);
  a1.x = fmaf(a1.x, sc1.x, sh1.x); a1.y = fmaf(a1.y, sc1.y, sh1.y);
  a1.z = fmaf(a1.z, sc1.z, sh1.z); a1.w = fmaf(a1.w, sc1.w, sh1.w);
  b0.x = fmaf(b0.x, sc0.x, sh0.x); b0.y = fmaf(b0.y, sc0.y, sh0.y);
  b0.z = fmaf(b0.z, sc0.z, sh0.z); b0.w = fmaf(b0.w, sc0.w, sh0.w);
  b1.x = fmaf(b1.x, sc1.x, sh1.x); b1.y = fmaf(b1.y, sc1.y, sh1.y);
  b1.z = fmaf(b1.z, sc1.z, sh1.z); b1.w = fmaf(b1.w, sc1.w, sh1.w);
  float d = a0.x * b0.x + a0.y * b0.y + a0.z * b0.z + a0.w * b0.w +
            a1.x * b1.x + a1.y * b1.y + a1.z * b1.z + a1.w * b1.w;
  d += __shfl_xor(d, 1);
  d += __shfl_xor(d, 2);
  d += __shfl_xor(d, 4);
  d += __shfl_xor(d, 8);
  if (l == 0) out[e] = d;
}

// ---------------- launch ----------------
extern "C" void kernel_launch(void* const* d_in, const int* in_sizes, int n_in,
                              void* d_out, int out_size, void* d_ws, size_t ws_size,
                              hipStream_t stream) {
  const float* x    = (const float*)d_in[0];
  const int* ei1    = (const int*)d_in[1];
  const int* ei2    = (const int*)d_in[2];
  const int* eli    = (const int*)d_in[3];
  const float* W1n1 = (const float*)d_in[4];
  const float* W1s1 = (const float*)d_in[5];
  const float* W1n2 = (const float*)d_in[6];
  const float* W1s2 = (const float*)d_in[7];
  const float* W2n1 = (const float*)d_in[8];
  const float* W2s1 = (const float*)d_in[9];
  const float* W2n2 = (const float*)d_in[10];
  const float* W2s2 = (const float*)d_in[11];
  const float* g1   = (const float*)d_in[12];
  const float* b1   = (const float*)d_in[13];
  const float* g2   = (const float*)d_in[14];
  const float* b2   = (const float*)d_in[15];
  float* out = (float*)d_out;

  const int N = NN, E = NE;
  const int EL = in_sizes[3] / 2;
  const int RB = (N + 63) / 64;       // gemm blocks (64 rows)
  const int G = RB * 4;               // 16-row tiles incl. padding (6252)

  char* w = (char*)d_ws;
  bf16x8* Xh = (bf16x8*)w; w += (size_t)G * 4 * 64 * 16;
  bf16x8* Xl = (bf16x8*)w; w += (size_t)G * 4 * 64 * 16;
  ushort* Hn1b = (ushort*)w; w += (size_t)N * D * 2;
  ushort* Hn2b = (ushort*)w; w += (size_t)N * D * 2;
  float* Hs = (float*)w; w += (size_t)N * D * 4;
  bf16x8* Wh1 = (bf16x8*)w; w += (size_t)24 * 4 * 64 * 16;
  bf16x8* Wl1 = (bf16x8*)w; w += (size_t)24 * 4 * 64 * 16;
  bf16x8* Wh2 = (bf16x8*)w; w += (size_t)24 * 4 * 64 * 16;
  bf16x8* Wl2 = (bf16x8*)w; w += (size_t)24 * 4 * 64 * 16;
  int* deg1 = (int*)w; w += (size_t)N * 4;
  int* deg2 = (int*)w; w += (size_t)N * 4;
  int* rp1  = (int*)w; w += (size_t)(N + 1) * 4;
  int* rp2  = (int*)w; w += (size_t)(N + 1) * 4;
  int* fl1  = (int*)w; w += (size_t)N * 4;
  int* fl2  = (int*)w; w += (size_t)N * 4;
  int* col1 = (int*)w; w += (size_t)E * 4;
  int* col2 = (int*)w; w += (size_t)E * 4;
  int* bsums = (int*)w; w += 256 * 4;
  float* inv1 = (float*)w; w += (size_t)N * 4;
  float* inv2 = (float*)w; w += (size_t)N * 4;
  float* stats1 = (float*)w; w += 2 * D * 4;
  float* stats2 = (float*)w; w += 2 * D * 4;
  float* coef1 = (float*)w; w += 2 * D * 4;
  float* coef2 = (float*)w; w += 2 * D * 4;

  hipMemsetAsync(deg1, 0, (size_t)2 * N * 4, stream);   // deg1+deg2 contiguous
  hipMemsetAsync(stats1, 0, 4 * D * 4, stream);         // stats1+stats2 contiguous

  int ebk = (E + 255) / 256;
  count_deg<<<ebk, 256, 0, stream>>>(ei1 + E, E, deg1);
  count_deg<<<ebk, 256, 0, stream>>>(ei2 + E, E, deg2);

  int nb = (N + 1023) / 1024;
  scan_block_sums<<<nb, 256, 0, stream>>>(deg1, bsums, N);
  scan_top<<<1, 64, 0, stream>>>(bsums, nb);
  scan_final<<<nb, 256, 0, stream>>>(deg1, bsums, rp1, fl1, inv1, N, E);
  scan_block_sums<<<nb, 256, 0, stream>>>(deg2, bsums, N);
  scan_top<<<1, 64, 0, stream>>>(bsums, nb);
  scan_final<<<nb, 256, 0, stream>>>(deg2, bsums, rp2, fl2, inv2, N, E);

  fill_csr<<<ebk, 256, 0, stream>>>(ei1, ei1 + E, fl1, col1, E);
  fill_csr<<<ebk, 256, 0, stream>>>(ei2, ei2 + E, fl2, col2, E);

  wpack<<<24, 256, 0, stream>>>(W1n1, W1n2, W1s1, W1s2, Wh1, Wl1);
  wpack<<<24, 256, 0, stream>>>(W2n1, W2n2, W2s1, W2s2, Wh2, Wl2);
  xpack<<<G, 256, 0, stream>>>(x, Xh, Xl, N);

  int gb = (N + 255) / 256;
  int agb = (N + 3) / 4;

  // ---- Layer 1 ----
  gemm_mfma<<<RB, 256, 0, stream>>>(Xh, Xl, Wh1, Wl1, Hn1b, Hn2b, Hs, N);
  fused_agg<<<agb, 256, 0, stream>>>(Hs, Hn1b, Hn2b, rp1, col1, inv1, rp2, col2, inv2, N);
  bn_stats<<<gb, 256, 0, stream>>>(Hs, stats1, N);
  bn_coef<<<1, 128, 0, stream>>>(stats1, g1, b1, coef1, 1.0f / N);
  bn_apply_pack<<<G, 256, 0, stream>>>(Hs, coef1, Xh, Xl, N);  // overwrite X packs

  // ---- Layer 2 ----
  gemm_mfma<<<RB, 256, 0, stream>>>(Xh, Xl, Wh2, Wl2, Hn1b, Hn2b, Hs, N);
  fused_agg<<<agb, 256, 0, stream>>>(Hs, Hn1b, Hn2b, rp1, col1, inv1, rp2, col2, inv2, N);
  bn_stats<<<gb, 256, 0, stream>>>(Hs, stats2, N);
  bn_coef<<<1, 128, 0, stream>>>(stats2, g2, b2, coef2, 1.0f / N);

  // ---- edge-label dots (BN affine fused) ----
  int db = (int)(((size_t)EL * 16 + 255) / 256);
  edge_dot_bn<<<db, 256, 0, stream>>>(Hs, coef2, eli, eli + EL, out, EL);
}

// Round 5
// 580.942 us; speedup vs baseline: 3.1576x; 1.2359x over previous
//
#include <hip/hip_runtime.h>

#define NN 100000
#define NE 500000
#define D 128
#define EPS 1e-5f
#define SLOPE 0.01f

typedef short bf16x8 __attribute__((ext_vector_type(8)));
typedef float f32x4 __attribute__((ext_vector_type(4)));

__device__ __forceinline__ ushort f2bf(float x) {
  uint u = __float_as_uint(x);
  u += 0x7FFF + ((u >> 16) & 1);
  return (ushort)(u >> 16);
}
__device__ __forceinline__ float bf2f(ushort h) {
  return __uint_as_float(((uint)h) << 16);
}

// ---------------- CSR build ----------------
__global__ void count_deg(const int* __restrict__ dst, int E, int* __restrict__ deg) {
  int i = blockIdx.x * 256 + threadIdx.x;
  if (i < E) atomicAdd(&deg[dst[i]], 1);
}

__global__ void scan_block_sums(const int* __restrict__ deg, int* __restrict__ bsums, int n) {
  __shared__ int red[256];
  int base = blockIdx.x * 1024;
  int s = 0;
  for (int i = threadIdx.x; i < 1024; i += 256) {
    int idx = base + i;
    if (idx < n) s += deg[idx];
  }
  red[threadIdx.x] = s;
  __syncthreads();
  for (int off = 128; off > 0; off >>= 1) {
    if (threadIdx.x < off) red[threadIdx.x] += red[threadIdx.x + off];
    __syncthreads();
  }
  if (threadIdx.x == 0) bsums[blockIdx.x] = red[0];
}

__global__ void scan_top(int* bsums, int nb) {
  if (threadIdx.x == 0 && blockIdx.x == 0) {
    int run = 0;
    for (int i = 0; i < nb; ++i) { int v = bsums[i]; bsums[i] = run; run += v; }
  }
}

__global__ void scan_final(const int* __restrict__ deg, const int* __restrict__ bsums,
                           int* __restrict__ row_ptr, int* __restrict__ fill,
                           float* __restrict__ invdeg, int n, int Etot) {
  __shared__ int buf[2][256];
  int base = blockIdx.x * 1024;
  int v[4];
  int s = 0;
#pragma unroll
  for (int j = 0; j < 4; ++j) {
    int idx = base + threadIdx.x * 4 + j;
    v[j] = (idx < n) ? deg[idx] : 0;
    s += v[j];
  }
  buf[0][threadIdx.x] = s;
  __syncthreads();
  int cur = 0;
  for (int d2 = 1; d2 < 256; d2 <<= 1) {
    int val = buf[cur][threadIdx.x];
    if (threadIdx.x >= d2) val += buf[cur][threadIdx.x - d2];
    buf[cur ^ 1][threadIdx.x] = val;
    __syncthreads();
    cur ^= 1;
  }
  int run = buf[cur][threadIdx.x] - s + bsums[blockIdx.x];
#pragma unroll
  for (int j = 0; j < 4; ++j) {
    int idx = base + threadIdx.x * 4 + j;
    if (idx < n) {
      row_ptr[idx] = run;
      fill[idx] = run;
      int dv = v[j] < 1 ? 1 : v[j];
      invdeg[idx] = 1.0f / (float)dv;
      run += v[j];
    }
  }
  if (blockIdx.x == 0 && threadIdx.x == 0) row_ptr[n] = Etot;
}

__global__ void fill_csr(const int* __restrict__ src, const int* __restrict__ dst,
                         int* __restrict__ fill, int* __restrict__ col, int E) {
  int i = blockIdx.x * 256 + threadIdx.x;
  if (i < E) {
    int p = atomicAdd(&fill[dst[i]], 1);
    col[p] = src[i];
  }
}

// ---------------- weight pack into B-fragment order (hi/lo split) ----------------
__global__ void wpack(const float* __restrict__ Wn1, const float* __restrict__ Wn2,
                      const float* __restrict__ Ws1, const float* __restrict__ Ws2,
                      bf16x8* __restrict__ Wh, bf16x8* __restrict__ Wl) {
  int ct = blockIdx.x;            // 0..23
  int ks = threadIdx.x >> 6;      // 0..3
  int l = threadIdx.x & 63;
  int col = (ct & 7) * 16 + (l & 15);
  int k0 = ks * 32 + (l >> 4) * 8;
  bf16x8 hv, lv;
#pragma unroll
  for (int j = 0; j < 8; ++j) {
    int k = k0 + j;
    float v;
    if (ct < 8)       v = Wn1[k * D + col];
    else if (ct < 16) v = Wn2[k * D + col];
    else              v = Ws1[k * D + col] + Ws2[k * D + col];
    ushort h = f2bf(v);
    float r = v - bf2f(h);
    hv[j] = (short)h;
    lv[j] = (short)f2bf(r);
  }
  int idx = (ct * 4 + ks) * 64 + l;
  Wh[idx] = hv;
  Wl[idx] = lv;
}

// ---------------- X pack into A-fragment order (hi/lo split) ----------------
__global__ void xpack(const float* __restrict__ X, bf16x8* __restrict__ Xh,
                      bf16x8* __restrict__ Xl, int M) {
  int g = blockIdx.x;
  int ks = threadIdx.x >> 6;
  int l = threadIdx.x & 63;
  int row = g * 16 + (l & 15);
  int c0 = ks * 32 + (l >> 4) * 8;
  bf16x8 hv, lv;
  if (row < M) {
    float4 a = *reinterpret_cast<const float4*>(X + (size_t)row * D + c0);
    float4 b = *reinterpret_cast<const float4*>(X + (size_t)row * D + c0 + 4);
    float xs[8] = {a.x, a.y, a.z, a.w, b.x, b.y, b.z, b.w};
#pragma unroll
    for (int j = 0; j < 8; ++j) {
      ushort h = f2bf(xs[j]);
      float r = xs[j] - bf2f(h);
      hv[j] = (short)h;
      lv[j] = (short)f2bf(r);
    }
  } else {
#pragma unroll
    for (int j = 0; j < 8; ++j) { hv[j] = 0; lv[j] = 0; }
  }
  int idx = (g * 4 + ks) * 64 + l;
  Xh[idx] = hv;
  Xl[idx] = lv;
}

// ---------------- MFMA GEMM: [Hn1b|Hn2b|Hs] = X @ [Wn1|Wn2|Wsum] ----------------
__global__ __launch_bounds__(256) void gemm_mfma(
    const bf16x8* __restrict__ Xh, const bf16x8* __restrict__ Xl,
    const bf16x8* __restrict__ Wh, const bf16x8* __restrict__ Wl,
    ushort* __restrict__ Hn1b, ushort* __restrict__ Hn2b,
    float* __restrict__ Hs, int M) {
  int w = __builtin_amdgcn_readfirstlane(threadIdx.x >> 6);
  int l = threadIdx.x & 63;
  int rb = blockIdx.x;

  f32x4 acc[4][6];
#pragma unroll
  for (int rt = 0; rt < 4; ++rt)
#pragma unroll
    for (int i = 0; i < 6; ++i)
      acc[rt][i] = (f32x4){0.f, 0.f, 0.f, 0.f};

#pragma unroll
  for (int ks = 0; ks < 4; ++ks) {
    bf16x8 Ah[4], Al[4];
#pragma unroll
    for (int rt = 0; rt < 4; ++rt) {
      int gi = ((rb * 4 + rt) * 4 + ks) * 64 + l;
      Ah[rt] = Xh[gi];
      Al[rt] = Xl[gi];
    }
#pragma unroll
    for (int i = 0; i < 6; ++i) {
      int ct = w + 4 * i;
      int wi = (ct * 4 + ks) * 64 + l;
      bf16x8 bh = Wh[wi];
      bf16x8 bl = Wl[wi];
#pragma unroll
      for (int rt = 0; rt < 4; ++rt) {
        acc[rt][i] = __builtin_amdgcn_mfma_f32_16x16x32_bf16(Ah[rt], bh, acc[rt][i], 0, 0, 0);
        acc[rt][i] = __builtin_amdgcn_mfma_f32_16x16x32_bf16(Ah[rt], bl, acc[rt][i], 0, 0, 0);
        acc[rt][i] = __builtin_amdgcn_mfma_f32_16x16x32_bf16(Al[rt], bh, acc[rt][i], 0, 0, 0);
      }
    }
  }

  int cq = l & 15;
  int rq = (l >> 4) * 4;
#pragma unroll
  for (int i = 0; i < 6; ++i) {
    int ct = w + 4 * i;  // wave-uniform
#pragma unroll
    for (int rt = 0; rt < 4; ++rt) {
      int R0 = rb * 64 + rt * 16 + rq;
#pragma unroll
      for (int r = 0; r < 4; ++r) {
        int R = R0 + r;
        if (R < M) {
          float v = acc[rt][i][r];
          if (ct < 8) {
            Hn1b[(size_t)R * D + ct * 16 + cq] = f2bf(v);
          } else if (ct < 16) {
            Hn2b[(size_t)R * D + (ct - 8) * 16 + cq] = f2bf(v);
          } else {
            Hs[(size_t)R * D + (ct - 16) * 16 + cq] = v;
          }
        }
      }
    }
  }
}

// ---- fused aggregation, latency-optimized: merged dual-type masked unroll-4 ----
// Hs[n] += inv1*sum Hn1b[col1] + inv2*sum Hn2b[col2]; also writes bf16 sidecar Hsb.
__global__ void fused_agg(float* __restrict__ Hs, ushort* __restrict__ Hsb,
                          const ushort* __restrict__ Hn1b, const ushort* __restrict__ Hn2b,
                          const int* __restrict__ rp1, const int* __restrict__ col1,
                          const float* __restrict__ inv1,
                          const int* __restrict__ rp2, const int* __restrict__ col2,
                          const float* __restrict__ inv2, int Nn) {
  int n = blockIdx.x * 4 + (threadIdx.x >> 6);
  if (n >= Nn) return;
  int t2 = (threadIdx.x & 63) * 2;
  int b1 = rp1[n], e1 = rp1[n + 1];
  int b2 = rp2[n], e2 = rp2[n + 1];
  int len1 = e1 - b1, len2 = e2 - b2;
  int lmax = len1 > len2 ? len1 : len2;

  float pa[4], pb[4], qa[4], qb[4];
#pragma unroll
  for (int k = 0; k < 4; ++k) { pa[k] = 0.f; pb[k] = 0.f; qa[k] = 0.f; qb[k] = 0.f; }

  for (int j = 0; j < lmax; j += 4) {
    uint v1[4], v2[4];
    float m1[4], m2[4];
#pragma unroll
    for (int k = 0; k < 4; ++k) {
      int a = j + k;
      int c1i = (len1 > 0) ? (b1 + (a < len1 ? a : len1 - 1)) : 0;
      int c2i = (len2 > 0) ? (b2 + (a < len2 ? a : len2 - 1)) : 0;
      m1[k] = (a < len1) ? 1.f : 0.f;
      m2[k] = (a < len2) ? 1.f : 0.f;
      v1[k] = *reinterpret_cast<const uint*>(Hn1b + (size_t)col1[c1i] * D + t2);
      v2[k] = *reinterpret_cast<const uint*>(Hn2b + (size_t)col2[c2i] * D + t2);
    }
#pragma unroll
    for (int k = 0; k < 4; ++k) {
      pa[k] = fmaf(m1[k], bf2f((ushort)(v1[k] & 0xFFFF)), pa[k]);
      pb[k] = fmaf(m1[k], bf2f((ushort)(v1[k] >> 16)), pb[k]);
      qa[k] = fmaf(m2[k], bf2f((ushort)(v2[k] & 0xFFFF)), qa[k]);
      qb[k] = fmaf(m2[k], bf2f((ushort)(v2[k] >> 16)), qb[k]);
    }
  }

  float i1 = inv1[n], i2 = inv2[n];
  float* hs = Hs + (size_t)n * D + t2;
  float2 sv = *reinterpret_cast<const float2*>(hs);
  float c0 = sv.x + (pa[0] + pa[1] + pa[2] + pa[3]) * i1 + (qa[0] + qa[1] + qa[2] + qa[3]) * i2;
  float c1 = sv.y + (pb[0] + pb[1] + pb[2] + pb[3]) * i1 + (qb[0] + qb[1] + qb[2] + qb[3]) * i2;
  float2 o; o.x = c0; o.y = c1;
  *reinterpret_cast<float2*>(hs) = o;
  uint packed = ((uint)f2bf(c1) << 16) | (uint)f2bf(c0);
  *reinterpret_cast<uint*>(Hsb + (size_t)n * D + t2) = packed;
}

// ---------------- BatchNorm stats (compact Hs [M][128]) ----------------
__global__ void bn_stats(const float* __restrict__ Hs, float* __restrict__ stats, int M) {
  int c = threadIdx.x & (D - 1);
  int half = threadIdx.x >> 7;
  int r = blockIdx.x * 256 + half;
  float s = 0.f, s2 = 0.f;
#pragma unroll 4
  for (int i = 0; i < 128; ++i, r += 2) {
    if (r < M) {
      float v = Hs[(size_t)r * D + c];
      s += v;
      s2 += v * v;
    }
  }
  atomicAdd(&stats[c], s);
  atomicAdd(&stats[D + c], s2);
}

// per-column affine: coef[c]=scale, coef[128+c]=shift
__global__ void bn_coef(const float* __restrict__ stats, const float* __restrict__ g,
                        const float* __restrict__ b, float* __restrict__ coef, float invM) {
  int c = threadIdx.x;
  if (c >= D) return;
  float mean = stats[c] * invM;
  float var = stats[D + c] * invM - mean * mean;
  float s = rsqrtf(var + EPS) * g[c];
  coef[c] = s;
  coef[D + c] = b[c] - mean * s;
}

// ---------------- BN + LeakyReLU + split-pack into A-fragment order ----------------
__global__ void bn_apply_pack(const float* __restrict__ Hs, const float* __restrict__ coef,
                              bf16x8* __restrict__ Ah, bf16x8* __restrict__ Al, int M) {
  int g = blockIdx.x;
  int ks = threadIdx.x >> 6;
  int l = threadIdx.x & 63;
  int row = g * 16 + (l & 15);
  int c0 = ks * 32 + (l >> 4) * 8;
  bf16x8 hv, lv;
  if (row < M) {
    float4 a = *reinterpret_cast<const float4*>(Hs + (size_t)row * D + c0);
    float4 b = *reinterpret_cast<const float4*>(Hs + (size_t)row * D + c0 + 4);
    float xs[8] = {a.x, a.y, a.z, a.w, b.x, b.y, b.z, b.w};
#pragma unroll
    for (int j = 0; j < 8; ++j) {
      int c = c0 + j;
      float v = fmaf(xs[j], coef[c], coef[D + c]);
      v = v > 0.f ? v : SLOPE * v;
      ushort h = f2bf(v);
      float r = v - bf2f(h);
      hv[j] = (short)h;
      lv[j] = (short)f2bf(r);
    }
  } else {
#pragma unroll
    for (int j = 0; j < 8; ++j) { hv[j] = 0; lv[j] = 0; }
  }
  int idx = (g * 4 + ks) * 64 + l;
  Ah[idx] = hv;
  Al[idx] = lv;
}

// ------- edge-label dots: gather bf16 rows, BN affine applied inline -------
__global__ void edge_dot_bn(const ushort* __restrict__ Hb, const float* __restrict__ coef,
                            const int* __restrict__ ea, const int* __restrict__ eb,
                            float* __restrict__ out, int EL) {
  int tt = blockIdx.x * 256 + threadIdx.x;
  int e = tt >> 4, l = tt & 15;
  if (e >= EL) return;
  int cb = l * 8;
  float4 sc0 = *reinterpret_cast<const float4*>(coef + cb);
  float4 sc1 = *reinterpret_cast<const float4*>(coef + cb + 4);
  float4 sh0 = *reinterpret_cast<const float4*>(coef + D + cb);
  float4 sh1 = *reinterpret_cast<const float4*>(coef + D + cb + 4);
  float sc[8] = {sc0.x, sc0.y, sc0.z, sc0.w, sc1.x, sc1.y, sc1.z, sc1.w};
  float sh[8] = {sh0.x, sh0.y, sh0.z, sh0.w, sh1.x, sh1.y, sh1.z, sh1.w};
  bf16x8 av = *reinterpret_cast<const bf16x8*>(Hb + (size_t)ea[e] * D + cb);
  bf16x8 bv = *reinterpret_cast<const bf16x8*>(Hb + (size_t)eb[e] * D + cb);
  float d = 0.f;
#pragma unroll
  for (int j = 0; j < 8; ++j) {
    float fa = fmaf(bf2f((ushort)av[j]), sc[j], sh[j]);
    float fb = fmaf(bf2f((ushort)bv[j]), sc[j], sh[j]);
    d = fmaf(fa, fb, d);
  }
  d += __shfl_xor(d, 1);
  d += __shfl_xor(d, 2);
  d += __shfl_xor(d, 4);
  d += __shfl_xor(d, 8);
  if (l == 0) out[e] = d;
}

// ---------------- launch ----------------
extern "C" void kernel_launch(void* const* d_in, const int* in_sizes, int n_in,
                              void* d_out, int out_size, void* d_ws, size_t ws_size,
                              hipStream_t stream) {
  const float* x    = (const float*)d_in[0];
  const int* ei1    = (const int*)d_in[1];
  const int* ei2    = (const int*)d_in[2];
  const int* eli    = (const int*)d_in[3];
  const float* W1n1 = (const float*)d_in[4];
  const float* W1s1 = (const float*)d_in[5];
  const float* W1n2 = (const float*)d_in[6];
  const float* W1s2 = (const float*)d_in[7];
  const float* W2n1 = (const float*)d_in[8];
  const float* W2s1 = (const float*)d_in[9];
  const float* W2n2 = (const float*)d_in[10];
  const float* W2s2 = (const float*)d_in[11];
  const float* g1   = (const float*)d_in[12];
  const float* b1   = (const float*)d_in[13];
  const float* g2   = (const float*)d_in[14];
  const float* b2   = (const float*)d_in[15];
  float* out = (float*)d_out;

  const int N = NN, E = NE;
  const int EL = in_sizes[3] / 2;
  const int RB = (N + 63) / 64;
  const int G = RB * 4;

  char* w = (char*)d_ws;
  bf16x8* Xh = (bf16x8*)w; w += (size_t)G * 4 * 64 * 16;
  bf16x8* Xl = (bf16x8*)w; w += (size_t)G * 4 * 64 * 16;
  ushort* Hn1b = (ushort*)w; w += (size_t)N * D * 2;
  ushort* Hn2b = (ushort*)w; w += (size_t)N * D * 2;
  ushort* Hsb  = (ushort*)w; w += (size_t)N * D * 2;
  float* Hs = (float*)w; w += (size_t)N * D * 4;
  bf16x8* Wh1 = (bf16x8*)w; w += (size_t)24 * 4 * 64 * 16;
  bf16x8* Wl1 = (bf16x8*)w; w += (size_t)24 * 4 * 64 * 16;
  bf16x8* Wh2 = (bf16x8*)w; w += (size_t)24 * 4 * 64 * 16;
  bf16x8* Wl2 = (bf16x8*)w; w += (size_t)24 * 4 * 64 * 16;
  int* deg1 = (int*)w; w += (size_t)N * 4;
  int* deg2 = (int*)w; w += (size_t)N * 4;
  int* rp1  = (int*)w; w += (size_t)(N + 1) * 4;
  int* rp2  = (int*)w; w += (size_t)(N + 1) * 4;
  int* fl1  = (int*)w; w += (size_t)N * 4;
  int* fl2  = (int*)w; w += (size_t)N * 4;
  int* col1 = (int*)w; w += (size_t)E * 4;
  int* col2 = (int*)w; w += (size_t)E * 4;
  int* bsums = (int*)w; w += 256 * 4;
  float* inv1 = (float*)w; w += (size_t)N * 4;
  float* inv2 = (float*)w; w += (size_t)N * 4;
  float* stats1 = (float*)w; w += 2 * D * 4;
  float* stats2 = (float*)w; w += 2 * D * 4;
  float* coef1 = (float*)w; w += 2 * D * 4;
  float* coef2 = (float*)w; w += 2 * D * 4;

  hipMemsetAsync(deg1, 0, (size_t)2 * N * 4, stream);   // deg1+deg2 contiguous
  hipMemsetAsync(stats1, 0, 4 * D * 4, stream);         // stats1+stats2 contiguous

  int ebk = (E + 255) / 256;
  count_deg<<<ebk, 256, 0, stream>>>(ei1 + E, E, deg1);
  count_deg<<<ebk, 256, 0, stream>>>(ei2 + E, E, deg2);

  int nb = (N + 1023) / 1024;
  scan_block_sums<<<nb, 256, 0, stream>>>(deg1, bsums, N);
  scan_top<<<1, 64, 0, stream>>>(bsums, nb);
  scan_final<<<nb, 256, 0, stream>>>(deg1, bsums, rp1, fl1, inv1, N, E);
  scan_block_sums<<<nb, 256, 0, stream>>>(deg2, bsums, N);
  scan_top<<<1, 64, 0, stream>>>(bsums, nb);
  scan_final<<<nb, 256, 0, stream>>>(deg2, bsums, rp2, fl2, inv2, N, E);

  fill_csr<<<ebk, 256, 0, stream>>>(ei1, ei1 + E, fl1, col1, E);
  fill_csr<<<ebk, 256, 0, stream>>>(ei2, ei2 + E, fl2, col2, E);

  wpack<<<24, 256, 0, stream>>>(W1n1, W1n2, W1s1, W1s2, Wh1, Wl1);
  wpack<<<24, 256, 0, stream>>>(W2n1, W2n2, W2s1, W2s2, Wh2, Wl2);
  xpack<<<G, 256, 0, stream>>>(x, Xh, Xl, N);

  int gb = (N + 255) / 256;
  int agb = (N + 3) / 4;

  // ---- Layer 1 ----
  gemm_mfma<<<RB, 256, 0, stream>>>(Xh, Xl, Wh1, Wl1, Hn1b, Hn2b, Hs, N);
  fused_agg<<<agb, 256, 0, stream>>>(Hs, Hsb, Hn1b, Hn2b, rp1, col1, inv1, rp2, col2, inv2, N);
  bn_stats<<<gb, 256, 0, stream>>>(Hs, stats1, N);
  bn_coef<<<1, 128, 0, stream>>>(stats1, g1, b1, coef1, 1.0f / N);
  bn_apply_pack<<<G, 256, 0, stream>>>(Hs, coef1, Xh, Xl, N);  // overwrite X packs

  // ---- Layer 2 ----
  gemm_mfma<<<RB, 256, 0, stream>>>(Xh, Xl, Wh2, Wl2, Hn1b, Hn2b, Hs, N);
  fused_agg<<<agb, 256, 0, stream>>>(Hs, Hsb, Hn1b, Hn2b, rp1, col1, inv1, rp2, col2, inv2, N);
  bn_stats<<<gb, 256, 0, stream>>>(Hs, stats2, N);
  bn_coef<<<1, 128, 0, stream>>>(stats2, g2, b2, coef2, 1.0f / N);

  // ---- edge-label dots (bf16 gathers, BN affine fused) ----
  int db = (int)(((size_t)EL * 16 + 255) / 256);
  edge_dot_bn<<<db, 256, 0, stream>>>(Hsb, coef2, eli, eli + EL, out, EL);
}